// Round 3
// baseline (151528.149 us; speedup 1.0000x reference)
//
#include <hip/hip_runtime.h>
#include <hip/hip_bf16.h>

// ---------------------------------------------------------------------------
// GraphS4mer forward, R3: producer/consumer pipelined GRU across 38 CUs.
//   gru_pipe: 38 blocks x 512 threads. Blocks 0..18 = L0 (producer),
//   blocks 19..37 = L1 (consumer). Producer g runs layer-0 recurrence for
//   sequences [16g,16g+16): 15 MFMA/wave/step, writes h0_t (bf16) to global,
//   releases flag[g][chunk] every 64 steps (agent-scope release after the
//   step barrier has drained all waves' stores). Consumer g spin-acquires
//   flag[g][c], then runs layer-1: 24 MFMA/wave/step (12 gi1 from h0 via
//   depth-2 register prefetch + 12 recurrent), window-means into xg.
//   Recurrent LDS state is double-buffered -> ONE barrier per step.
// ---------------------------------------------------------------------------

#define NSEQ   304
#define TT     2048
#define HH     128
#define NNODE  19
#define NDYN   8
#define NGRAPH 128
#define PITCH  136
#define CHUNK  64
#define NCHUNK (TT / CHUNK)     // 32

typedef __bf16 bf16x8 __attribute__((ext_vector_type(8)));
typedef float  f32x4  __attribute__((ext_vector_type(4)));

static __device__ __forceinline__ f32x4 mfma16(bf16x8 a, bf16x8 b, f32x4 c) {
  return __builtin_amdgcn_mfma_f32_16x16x32_bf16(a, b, c, 0, 0, 0);
}
static __device__ __forceinline__ float fast_sigmoid(float x) {
  const float e = __builtin_amdgcn_exp2f(-1.4426950408889634f * x);
  return __builtin_amdgcn_rcpf(1.f + e);
}
static __device__ __forceinline__ float fast_tanh(float x) {
  const float e = __builtin_amdgcn_exp2f(2.8853900817779268f * x);
  return 1.f - 2.f * __builtin_amdgcn_rcpf(1.f + e);
}

__global__ __launch_bounds__(512, 2) void gru_pipe(
    const float* __restrict__ x,
    const float* __restrict__ Wih0, const float* __restrict__ Whh0,
    const float* __restrict__ bih0, const float* __restrict__ bhh0,
    const float* __restrict__ Wih1, const float* __restrict__ Whh1,
    const float* __restrict__ bih1, const float* __restrict__ bhh1,
    __bf16* __restrict__ h0g, float* __restrict__ xg,
    int* __restrict__ flags)
{
  __shared__ __align__(16) __bf16 sH[2][16 * PITCH];

  const int tid = threadIdx.x;
  const int w   = tid >> 6;
  const int l   = tid & 63;
  const int lm  = l & 15;
  const int lq  = l >> 4;
  const bool producer = (blockIdx.x < NNODE);
  const int g   = producer ? blockIdx.x : blockIdx.x - NNODE;
  const int j   = 16 * w + lm;
  const int aoff = lm * PITCH + lq * 8;
  const f32x4 z4 = {0.f, 0.f, 0.f, 0.f};

  for (int i = tid; i < 16 * PITCH; i += 512) {
    sH[0][i] = (__bf16)0.f;
  }

  if (producer) {
    // ---- layer 0 ----
    bf16x8 bI0[3], bH0[3][4];
    #pragma unroll
    for (int gs = 0; gs < 3; ++gs) {
      const int row = 128 * gs + j;
      {
        const float* p = Wih0 + row * 32 + lq * 8;
        bf16x8 f;
        #pragma unroll
        for (int u = 0; u < 8; ++u) f[u] = (__bf16)p[u];
        bI0[gs] = f;
      }
      #pragma unroll
      for (int kc = 0; kc < 4; ++kc) {
        const float* p = Whh0 + row * 128 + kc * 32 + lq * 8;
        bf16x8 f;
        #pragma unroll
        for (int u = 0; u < 8; ++u) f[u] = (__bf16)p[u];
        bH0[gs][kc] = f;
      }
    }
    const float Br  = bih0[j] + bhh0[j];
    const float Bz  = bih0[128 + j] + bhh0[128 + j];
    const float bin = bih0[256 + j];
    const float bhn = bhh0[256 + j];

    const float* xrow = x + ((size_t)(g * 16 + lm) * TT) * 32 + lq * 8;
    float4 xb[8];
    float hp[4] = {0.f, 0.f, 0.f, 0.f};
    __syncthreads();

    for (int t = 0; t < TT; ++t) {
      if ((t & 3) == 0) {
        #pragma unroll
        for (int st = 0; st < 4; ++st) {
          xb[2 * st]     = *(const float4*)(xrow + (size_t)(t + st) * 32);
          xb[2 * st + 1] = *(const float4*)(xrow + (size_t)(t + st) * 32 + 4);
        }
      }
      bf16x8 a0;
      {
        const float4 fa = xb[2 * (t & 3)], fb = xb[2 * (t & 3) + 1];
        a0[0] = (__bf16)fa.x; a0[1] = (__bf16)fa.y;
        a0[2] = (__bf16)fa.z; a0[3] = (__bf16)fa.w;
        a0[4] = (__bf16)fb.x; a0[5] = (__bf16)fb.y;
        a0[6] = (__bf16)fb.z; a0[7] = (__bf16)fb.w;
      }
      bf16x8 ah[4];
      #pragma unroll
      for (int kc = 0; kc < 4; ++kc)
        ah[kc] = *(const bf16x8*)&sH[t & 1][aoff + kc * 32];

      f32x4 Cr = mfma16(a0, bI0[0], z4);
      f32x4 Cz = mfma16(a0, bI0[1], z4);
      f32x4 Cn = mfma16(a0, bI0[2], z4);
      f32x4 Cm = z4;
      #pragma unroll
      for (int kc = 0; kc < 4; ++kc) {
        Cr = mfma16(ah[kc], bH0[0][kc], Cr);
        Cz = mfma16(ah[kc], bH0[1][kc], Cz);
        Cm = mfma16(ah[kc], bH0[2][kc], Cm);
      }
      __bf16* hg = h0g + ((size_t)(g * TT + t) * 16) * 128;
      #pragma unroll
      for (int q = 0; q < 4; ++q) {
        const float r  = fast_sigmoid(Cr[q] + Br);
        const float zz = fast_sigmoid(Cz[q] + Bz);
        const float n  = fast_tanh(Cn[q] + bin + r * (Cm[q] + bhn));
        const float h  = n + zz * (hp[q] - n);
        hp[q] = h;
        const __bf16 hb = (__bf16)h;
        sH[(t + 1) & 1][(lq * 4 + q) * PITCH + j] = hb;
        hg[(lq * 4 + q) * 128 + j] = hb;
      }
      __syncthreads();   // drains all waves' h0 stores too
      if ((t & (CHUNK - 1)) == CHUNK - 1 && tid == 0) {
        __hip_atomic_store(&flags[g * NCHUNK + (t >> 6)], 1,
                           __ATOMIC_RELEASE, __HIP_MEMORY_SCOPE_AGENT);
      }
    }
  } else {
    // ---- layer 1 ----
    bf16x8 bI1[3][4], bH1[3][4];
    #pragma unroll
    for (int gs = 0; gs < 3; ++gs) {
      const int row = 128 * gs + j;
      #pragma unroll
      for (int kc = 0; kc < 4; ++kc) {
        const float* p0 = Wih1 + row * 128 + kc * 32 + lq * 8;
        const float* p1 = Whh1 + row * 128 + kc * 32 + lq * 8;
        bf16x8 f0, f1;
        #pragma unroll
        for (int u = 0; u < 8; ++u) { f0[u] = (__bf16)p0[u]; f1[u] = (__bf16)p1[u]; }
        bI1[gs][kc] = f0; bH1[gs][kc] = f1;
      }
    }
    const float Br  = bih1[j] + bhh1[j];
    const float Bz  = bih1[128 + j] + bhh1[128 + j];
    const float bin = bih1[256 + j];
    const float bhn = bhh1[256 + j];

    float hp[4]   = {0.f, 0.f, 0.f, 0.f};
    float hsum[4] = {0.f, 0.f, 0.f, 0.f};
    bf16x8 hpf[2][4];
    __syncthreads();

    for (int c = 0; c < NCHUNK; ++c) {
      if (tid == 0) {
        while (__hip_atomic_load(&flags[g * NCHUNK + c],
                                 __ATOMIC_ACQUIRE, __HIP_MEMORY_SCOPE_AGENT) == 0) {
          __builtin_amdgcn_s_sleep(16);
        }
      }
      __syncthreads();

      const int t0 = c * CHUNK;
      {
        const __bf16* h0 = h0g + ((size_t)(g * TT + t0) * 16 + lm) * 128 + lq * 8;
        const __bf16* h1 = h0g + ((size_t)(g * TT + t0 + 1) * 16 + lm) * 128 + lq * 8;
        #pragma unroll
        for (int kc = 0; kc < 4; ++kc) {
          hpf[0][kc] = *(const bf16x8*)(h0 + kc * 32);
          hpf[1][kc] = *(const bf16x8*)(h1 + kc * 32);
        }
      }

      for (int tl = 0; tl < CHUNK; ++tl) {
        const int t = t0 + tl;
        bf16x8 ag[4];
        #pragma unroll
        for (int kc = 0; kc < 4; ++kc) ag[kc] = hpf[tl & 1][kc];
        if (tl + 2 < CHUNK) {
          const __bf16* hn = h0g + ((size_t)(g * TT + t + 2) * 16 + lm) * 128 + lq * 8;
          #pragma unroll
          for (int kc = 0; kc < 4; ++kc)
            hpf[tl & 1][kc] = *(const bf16x8*)(hn + kc * 32);
        }
        bf16x8 ah[4];
        #pragma unroll
        for (int kc = 0; kc < 4; ++kc)
          ah[kc] = *(const bf16x8*)&sH[t & 1][aoff + kc * 32];

        f32x4 Dr = z4, Dz = z4, Dn = z4, Dm = z4;
        #pragma unroll
        for (int kc = 0; kc < 4; ++kc) {
          Dr = mfma16(ag[kc], bI1[0][kc], Dr);
          Dz = mfma16(ag[kc], bI1[1][kc], Dz);
          Dn = mfma16(ag[kc], bI1[2][kc], Dn);
        }
        #pragma unroll
        for (int kc = 0; kc < 4; ++kc) {
          Dr = mfma16(ah[kc], bH1[0][kc], Dr);
          Dz = mfma16(ah[kc], bH1[1][kc], Dz);
          Dm = mfma16(ah[kc], bH1[2][kc], Dm);
        }
        #pragma unroll
        for (int q = 0; q < 4; ++q) {
          const float r  = fast_sigmoid(Dr[q] + Br);
          const float zz = fast_sigmoid(Dz[q] + Bz);
          const float n  = fast_tanh(Dn[q] + bin + r * (Dm[q] + bhn));
          const float h  = n + zz * (hp[q] - n);
          hp[q] = h;
          hsum[q] += h;
          sH[(t + 1) & 1][(lq * 4 + q) * PITCH + j] = (__bf16)h;
        }
        if ((t & 255) == 255) {
          const int win = t >> 8;
          #pragma unroll
          for (int q = 0; q < 4; ++q) {
            const int seq  = g * 16 + lq * 4 + q;
            const int b    = seq / NNODE;
            const int node = seq - b * NNODE;
            xg[((size_t)(b * NDYN + win) * NNODE + node) * HH + j] =
                hsum[q] * (1.f / 256.f);
            hsum[q] = 0.f;
          }
        }
        __syncthreads();
      }
    }
  }
}

// ---------------------------------------------------------------------------
// Per-graph stage (unchanged — verified, negligible time).
// ---------------------------------------------------------------------------
static __device__ __forceinline__ float blockReduce256(float v, float* sRed)
{
  const int tid = threadIdx.x;
  __syncthreads();
  sRed[tid] = v;
  __syncthreads();
  #pragma unroll
  for (int st = 128; st >= 1; st >>= 1) {
    if (tid < st) sRed[tid] += sRed[tid + st];
    __syncthreads();
  }
  return sRed[0];
}

__global__ __launch_bounds__(256) void graph_kernel(
    const float* __restrict__ xg,
    const float* __restrict__ Wq, const float* __restrict__ Wk,
    const float* __restrict__ Wl, const float* __restrict__ Wr,
    const float* __restrict__ bs, const float* __restrict__ Wc,
    float* __restrict__ out)
{
  const int tid = threadIdx.x;
  const int bp = blockIdx.x;

  __shared__ float sX[NNODE * HH];
  __shared__ float sQ[NNODE * HH];
  __shared__ float sK[NNODE * HH];
  __shared__ float sG[NNODE * NNODE];
  __shared__ float sA[NNODE * NNODE];
  __shared__ float sS[NNODE * NNODE];
  __shared__ float sNorm[NNODE];
  __shared__ float sDis[NNODE];
  __shared__ float sDeg[NNODE];
  __shared__ float sThr;
  __shared__ float sRed[256];

  for (int idx = tid; idx < NNODE * HH; idx += 256)
    sX[idx] = xg[(size_t)bp * NNODE * HH + idx];
  __syncthreads();

  if (tid < NNODE) {
    float acc = 0.f;
    const float* xv = &sX[tid * HH];
    #pragma unroll 4
    for (int d = 0; d < HH; ++d) acc += xv[d] * xv[d];
    sNorm[tid] = 1.f / sqrtf(acc);
  }
  for (int e = tid; e < NNODE * NNODE; e += 256) {
    const int n = e / NNODE, m = e % NNODE;
    float acc = 0.f;
    const float* a = &sX[n * HH];
    const float* b = &sX[m * HH];
    #pragma unroll 4
    for (int d = 0; d < HH; ++d) acc += a[d] * b[d];
    sG[e] = acc;
  }
  for (int e = tid; e < NNODE * NNODE; e += 256) sA[e] = 0.f;
  __syncthreads();

  if (tid < NNODE) {
    const int r = tid;
    const float nr = sNorm[r];
    float v0 = -1e30f, v1 = -1e30f, v2 = -1e30f;
    int i0 = 0, i1 = 0, i2 = 0;
    for (int m = 0; m < NNODE; ++m) {
      const float v = sG[r * NNODE + m] * nr * sNorm[m];
      if (v > v0)      { v2 = v1; i2 = i1; v1 = v0; i1 = i0; v0 = v; i0 = m; }
      else if (v > v1) { v2 = v1; i2 = i1; v1 = v;  i1 = m; }
      else if (v > v2) { v2 = v;  i2 = m; }
    }
    sA[r * NNODE + i0] = fmaxf(v0, 0.f);
    sA[r * NNODE + i1] = fmaxf(v1, 0.f);
    sA[r * NNODE + i2] = fmaxf(v2, 0.f);
  }
  __syncthreads();

  {
    float t0 = 0.f, t1 = 0.f;
    if (tid < 361) {
      const int n = tid / NNODE, m = tid % NNODE;
      t0 = (n == m) ? 1.f : 0.5f * (sA[n * NNODE + m] + sA[m * NNODE + n]);
    }
    if (tid + 256 < 361) {
      const int e = tid + 256;
      const int n = e / NNODE, m = e % NNODE;
      t1 = (n == m) ? 1.f : 0.5f * (sA[n * NNODE + m] + sA[m * NNODE + n]);
    }
    __syncthreads();
    if (tid < 361) sA[tid] = t0;
    if (tid + 256 < 361) sA[tid + 256] = t1;
  }

  for (int o = tid; o < NNODE * HH; o += 256) {
    const int n = o >> 7, hh = o & 127;
    float aq = 0.f, ak = 0.f;
    const float* xv = &sX[n * HH];
    const float* wq = &Wq[hh * HH];
    const float* wk = &Wk[hh * HH];
    #pragma unroll 4
    for (int d = 0; d < HH; ++d) { const float xx = xv[d]; aq += xx * wq[d]; ak += xx * wk[d]; }
    sQ[o] = aq; sK[o] = ak;
  }
  __syncthreads();

  for (int e = tid; e < NNODE * NNODE; e += 256) {
    const int n = e / NNODE, m = e % NNODE;
    float acc = 0.f;
    const float* a = &sQ[n * HH];
    const float* b = &sK[m * HH];
    #pragma unroll 4
    for (int d = 0; d < HH; ++d) acc += a[d] * b[d];
    sS[e] = acc * 0.08838834764831845f;
  }
  __syncthreads();
  if (tid < NNODE) {
    const int r = tid;
    float mx = -1e30f;
    for (int m = 0; m < NNODE; ++m) mx = fmaxf(mx, sS[r * NNODE + m]);
    float sum = 0.f;
    for (int m = 0; m < NNODE; ++m) sum += expf(sS[r * NNODE + m] - mx);
    const float inv = 1.f / sum;
    for (int m = 0; m < NNODE; ++m)
      sS[r * NNODE + m] = expf(sS[r * NNODE + m] - mx) * inv;
  }
  __syncthreads();

  for (int e = tid; e < NNODE * NNODE; e += 256) {
    const int n = e / NNODE, m = e % NNODE;
    sA[e] = 0.1f * sA[e] + 0.45f * (sS[n * NNODE + m] + sS[m * NNODE + n]);
  }
  __syncthreads();

  for (int e = tid; e < NNODE * NNODE; e += 256) {
    const float v = sA[e];
    int cg = 0, ce = 0;
    for (int f = 0; f < NNODE * NNODE; ++f) {
      const float u = sA[f];
      cg += (u > v);
      ce += (u == v);
    }
    if (cg <= 180 && cg + ce > 180) sThr = v;
  }
  __syncthreads();
  {
    const float thr = sThr;
    for (int e = tid; e < NNODE * NNODE; e += 256)
      sA[e] = (sA[e] > thr) ? sA[e] : 0.f;
  }
  __syncthreads();

  if (tid < NNODE) {
    const int r = tid;
    float dsum = 0.f;
    int cnt = 0;
    for (int m = 0; m < NNODE; ++m) {
      const float v = sA[r * NNODE + m];
      dsum += v;
      if (m != r && v > 0.f) ++cnt;
    }
    sDis[r] = (dsum > 0.f) ? 1.f / sqrtf(dsum) : 0.f;
    sDeg[r] = (float)(cnt < 1 ? 1 : cnt);
  }
  __syncthreads();

  float regp = 0.f;
  for (int e = tid; e < NNODE * NNODE; e += 256) {
    const int n = e / NNODE, m = e % NNODE;
    const float Lnm = ((n == m) ? 1.f : 0.f) - sDis[n] * sDis[m] * sA[e];
    regp += Lnm * sG[e];
  }
  {
    const float tr = blockReduce256(regp, sRed);
    if (tid == 0)
      atomicAdd(out + 16, tr * (1.f / (16384.f * (float)NGRAPH)));
  }
  __syncthreads();

  for (int o = tid; o < NNODE * HH; o += 256) {
    const int n = o >> 7, d = o & 127;
    float acc = 0.f;
    for (int m = 0; m < NNODE; ++m)
      if (m != n && sA[n * NNODE + m] > 0.f) acc += sX[m * HH + d];
    sQ[o] = acc / sDeg[n];
  }
  __syncthreads();

  float lgp = 0.f;
  for (int o = tid; o < NNODE * HH; o += 256) {
    const int n = o >> 7, hh = o & 127;
    float acc = bs[hh];
    const float* av = &sQ[n * HH];
    const float* xv = &sX[n * HH];
    const float* wl = &Wl[hh * HH];
    const float* wr = &Wr[hh * HH];
    #pragma unroll 4
    for (int d = 0; d < HH; ++d) acc += av[d] * wl[d] + xv[d] * wr[d];
    lgp += fmaxf(acc, 0.f) * Wc[hh];
  }
  {
    const float tot = blockReduce256(lgp, sRed);
    if (tid == 0)
      atomicAdd(out + (bp >> 3), tot * 0.125f);
  }
}

__global__ void init_kernel(float* __restrict__ out, const float* __restrict__ bc,
                            int* __restrict__ flags)
{
  const int i = threadIdx.x;
  if (i < 16) out[i] = bc[0];
  else if (i == 16) out[16] = 0.f;
  for (int f = i; f < NNODE * NCHUNK; f += 1024) flags[f] = 0;
}

// ---------------------------------------------------------------------------
extern "C" void kernel_launch(void* const* d_in, const int* in_sizes, int n_in,
                              void* d_out, int out_size, void* d_ws, size_t ws_size,
                              hipStream_t stream)
{
  const float* x    = (const float*)d_in[0];
  const float* Wih0 = (const float*)d_in[1];
  const float* Whh0 = (const float*)d_in[2];
  const float* bih0 = (const float*)d_in[3];
  const float* bhh0 = (const float*)d_in[4];
  const float* Wih1 = (const float*)d_in[5];
  const float* Whh1 = (const float*)d_in[6];
  const float* bih1 = (const float*)d_in[7];
  const float* bhh1 = (const float*)d_in[8];
  const float* Wq   = (const float*)d_in[9];
  const float* Wk   = (const float*)d_in[10];
  const float* Wl   = (const float*)d_in[11];
  const float* Wr   = (const float*)d_in[12];
  const float* bsg  = (const float*)d_in[13];
  const float* Wc   = (const float*)d_in[14];
  const float* bc   = (const float*)d_in[15];
  float* out = (float*)d_out;

  const size_t H0_BYTES = (size_t)NSEQ * TT * HH * sizeof(__bf16);  // 159.4 MB
  const size_t XG_BYTES = (size_t)NGRAPH * NNODE * HH * sizeof(float);
  __bf16* h0g  = (__bf16*)d_ws;
  float*  xg   = (float*)((char*)d_ws + H0_BYTES);
  int*    flags = (int*)((char*)d_ws + H0_BYTES + XG_BYTES);

  init_kernel<<<1, 1024, 0, stream>>>(out, bc, flags);
  gru_pipe<<<2 * NNODE, 512, 0, stream>>>(
      x, Wih0, Whh0, bih0, bhh0, Wih1, Whh1, bih1, bhh1, h0g, xg, flags);
  graph_kernel<<<NGRAPH, 256, 0, stream>>>(xg, Wq, Wk, Wl, Wr, bsg, Wc, out);
}

// Round 4
// 3136.778 us; speedup vs baseline: 48.3069x; 48.3069x over previous
//
#include <hip/hip_runtime.h>
#include <hip/hip_bf16.h>

// ---------------------------------------------------------------------------
// GraphS4mer forward, R4: fused 2-layer GRU, 19 blocks x 512 threads.
//   - Weights pre-converted to bf16 in MFMA B-fragment order (wprep) and held
//     in VGPRs (amdgpu_waves_per_eu(2,2) -> 256-reg budget, no occupancy chase).
//   - x pre-converted to bf16 A-fragment layout (xprep): 1 b128 load/step.
//   - L1 skewed one step behind L0 -> ONE __syncthreads per step; L1's gi
//     input (h0_{t-1}) reuses the exact fragment L0 reads for its recurrence.
//   - 39 v_mfma_f32_16x16x32_bf16 per wave-step, 8 ds_read_b128 per wave-step.
//   R3's cross-CU pipeline removed (agent-atomic flag visibility ~ms: G16).
// ---------------------------------------------------------------------------

#define NSEQ   304
#define TT     2048
#define HH     128
#define NNODE  19
#define NDYN   8
#define NGRAPH 128
#define PITCH  136            // bf16 row pitch: 272B = 17*16 -> b128-aligned

typedef __bf16 bf16x8 __attribute__((ext_vector_type(8)));
typedef float  f32x4  __attribute__((ext_vector_type(4)));

static __device__ __forceinline__ f32x4 mfma16(bf16x8 a, bf16x8 b, f32x4 c) {
  return __builtin_amdgcn_mfma_f32_16x16x32_bf16(a, b, c, 0, 0, 0);
}

// GRU gate update: r=sig(cr+Br), z=sig(cz+Bz), n=tanh(cn+bin + r*(cm+bhn)),
// h = n + z*(hp-n).  nBr/nBz are -log2(e)*(bih+bhh) prefolded.
static __device__ __forceinline__ float gate_step(
    float cr, float cz, float cn, float cm,
    float nBr, float nBz, float bin, float bhn, float hp)
{
  const float er = __builtin_amdgcn_exp2f(__builtin_fmaf(cr, -1.4426950408889634f, nBr));
  const float ez = __builtin_amdgcn_exp2f(__builtin_fmaf(cz, -1.4426950408889634f, nBz));
  const float r  = __builtin_amdgcn_rcpf(1.f + er);
  const float z  = __builtin_amdgcn_rcpf(1.f + ez);
  const float gn = __builtin_fmaf(r, cm + bhn, cn + bin);
  const float en = __builtin_amdgcn_exp2f(gn * 2.8853900817779268f);   // e^(2gn)
  const float nn = __builtin_fmaf(__builtin_amdgcn_rcpf(1.f + en), -2.f, 1.f);
  return __builtin_fmaf(z, hp - nn, nn);
}

// ---------------------------------------------------------------------------
// Prep: weights -> bf16 fragment order. dst[((w*3+gs)*nk+kc)*64+l][8] =
//   src[(128*gs+16*w+(l&15))*K + kc*32 + (l>>4)*8 + u]
// ---------------------------------------------------------------------------
__global__ void wprep_kernel(const float* __restrict__ src, __bf16* __restrict__ dst,
                             int K, int nk)
{
  const int i = blockIdx.x * 256 + threadIdx.x;
  const int total = 8 * 3 * nk * 64;
  if (i >= total) return;
  const int l = i & 63;
  int rest = i >> 6;
  const int kc = rest % nk; rest /= nk;
  const int gs = rest % 3;
  const int w  = rest / 3;
  const int row = 128 * gs + 16 * w + (l & 15);
  const float* s = src + (size_t)row * K + kc * 32 + (l >> 4) * 8;
  bf16x8 v;
  #pragma unroll
  for (int u = 0; u < 8; ++u) v[u] = (__bf16)s[u];
  *(bf16x8*)&dst[(size_t)i * 8] = v;
}

// x -> bf16 A-fragment layout: xb[((g*TT+t)*64+l)*8+u] =
//   x[(g*16+(l&15))*TT*32 + t*32 + (l>>4)*8 + u]
__global__ void xprep_kernel(const float* __restrict__ x, __bf16* __restrict__ xb)
{
  const int i = blockIdx.x * 256 + threadIdx.x;
  if (i >= NNODE * TT * 64) return;
  const int l = i & 63;
  const int t = (i >> 6) & (TT - 1);
  const int g = i >> 17;                       // 64*2048 = 2^17
  const float* s = x + ((size_t)(g * 16 + (l & 15)) * TT + t) * 32 + (l >> 4) * 8;
  bf16x8 v;
  #pragma unroll
  for (int u = 0; u < 8; ++u) v[u] = (__bf16)s[u];
  *(bf16x8*)&xb[(size_t)i * 8] = v;
}

// ---------------------------------------------------------------------------
__global__ __launch_bounds__(512) __attribute__((amdgpu_waves_per_eu(2, 2)))
void gru2_kernel(
    const __bf16* __restrict__ xb,
    const __bf16* __restrict__ wI0, const __bf16* __restrict__ wH0,
    const __bf16* __restrict__ wI1, const __bf16* __restrict__ wH1,
    const float* __restrict__ bih0, const float* __restrict__ bhh0,
    const float* __restrict__ bih1, const float* __restrict__ bhh1,
    float* __restrict__ xg)
{
  __shared__ __align__(16) __bf16 sH0[2][16 * PITCH];
  __shared__ __align__(16) __bf16 sH1[2][16 * PITCH];

  const int tid = threadIdx.x;
  const int w   = tid >> 6;
  const int l   = tid & 63;
  const int lm  = l & 15;
  const int lq  = l >> 4;
  const int g   = blockIdx.x;
  const int j   = 16 * w + lm;
  const int aoff = lm * PITCH + lq * 8;
  const f32x4 z4 = {0.f, 0.f, 0.f, 0.f};

  // ---- weights: bf16 fragments, register-resident ----
  bf16x8 bI0[3], bH0[3][4], bI1[3][4], bH1[3][4];
  #pragma unroll
  for (int gs = 0; gs < 3; ++gs)
    bI0[gs] = *(const bf16x8*)&wI0[(size_t)((w * 3 + gs) * 64 + l) * 8];
  #pragma unroll
  for (int gs = 0; gs < 3; ++gs)
    #pragma unroll
    for (int kc = 0; kc < 4; ++kc) {
      const size_t fi = (size_t)(((w * 3 + gs) * 4 + kc) * 64 + l) * 8;
      bH0[gs][kc] = *(const bf16x8*)&wH0[fi];
      bI1[gs][kc] = *(const bf16x8*)&wI1[fi];
      bH1[gs][kc] = *(const bf16x8*)&wH1[fi];
    }

  const float L2E = 1.4426950408889634f;
  const float nBr0 = -L2E * (bih0[j] + bhh0[j]);
  const float nBz0 = -L2E * (bih0[128 + j] + bhh0[128 + j]);
  const float bin0 = bih0[256 + j], bhn0 = bhh0[256 + j];
  const float nBr1 = -L2E * (bih1[j] + bhh1[j]);
  const float nBz1 = -L2E * (bih1[128 + j] + bhh1[128 + j]);
  const float bin1 = bih1[256 + j], bhn1 = bhh1[256 + j];

  for (int i = tid; i < 16 * PITCH; i += 512) {
    sH0[0][i] = (__bf16)0.f; sH0[1][i] = (__bf16)0.f;
    sH1[0][i] = (__bf16)0.f; sH1[1][i] = (__bf16)0.f;
  }

  float h0p[4]  = {0.f, 0.f, 0.f, 0.f};
  float h1p[4]  = {0.f, 0.f, 0.f, 0.f};
  float hsum[4] = {0.f, 0.f, 0.f, 0.f};

  const __bf16* xrow = xb + (size_t)g * TT * 512 + l * 8;
  bf16x8 a0 = *(const bf16x8*)xrow;          // t = 0 fragment
  __syncthreads();

  for (int t = 0; t < TT; ++t) {
    __bf16*       h0w = sH0[t & 1];          // h0_t
    const __bf16* h0r = sH0[(t + 1) & 1];    // h0_{t-1}
    __bf16*       h1w = sH1[(t + 1) & 1];    // h1_{t-1}
    const __bf16* h1r = sH1[t & 1];          // h1_{t-2}

    bf16x8 ah0[4], ah1[4];
    #pragma unroll
    for (int kc = 0; kc < 4; ++kc) ah0[kc] = *(const bf16x8*)&h0r[aoff + kc * 32];
    #pragma unroll
    for (int kc = 0; kc < 4; ++kc) ah1[kc] = *(const bf16x8*)&h1r[aoff + kc * 32];

    // prefetch next-step x fragment (consumed after next barrier)
    bf16x8 a0n = *(const bf16x8*)(xrow + (size_t)((t + 1) & (TT - 1)) * 512);

    // ---- L1 MFMAs first (step t-1): gi from h0_{t-1} (=ah0), rec from ah1
    f32x4 Dr = z4, Dz = z4, Dn = z4, Dm = z4;
    if (t > 0) {
      #pragma unroll
      for (int kc = 0; kc < 4; ++kc) {
        Dr = mfma16(ah0[kc], bI1[0][kc], Dr);
        Dz = mfma16(ah0[kc], bI1[1][kc], Dz);
        Dn = mfma16(ah0[kc], bI1[2][kc], Dn);
      }
      #pragma unroll
      for (int kc = 0; kc < 4; ++kc) {
        Dr = mfma16(ah1[kc], bH1[0][kc], Dr);
        Dz = mfma16(ah1[kc], bH1[1][kc], Dz);
        Dm = mfma16(ah1[kc], bH1[2][kc], Dm);
      }
    }

    // ---- L0 MFMAs (step t)
    f32x4 Cr = mfma16(a0, bI0[0], z4);
    f32x4 Cz = mfma16(a0, bI0[1], z4);
    f32x4 Cn = mfma16(a0, bI0[2], z4);
    f32x4 Cm = z4;
    #pragma unroll
    for (int kc = 0; kc < 4; ++kc) {
      Cr = mfma16(ah0[kc], bH0[0][kc], Cr);
      Cz = mfma16(ah0[kc], bH0[1][kc], Cz);
      Cm = mfma16(ah0[kc], bH0[2][kc], Cm);
    }

    // ---- gates
    #pragma unroll
    for (int q = 0; q < 4; ++q) {
      const float h = gate_step(Cr[q], Cz[q], Cn[q], Cm[q],
                                nBr0, nBz0, bin0, bhn0, h0p[q]);
      h0p[q] = h;
      h0w[(lq * 4 + q) * PITCH + j] = (__bf16)h;
    }
    if (t > 0) {
      #pragma unroll
      for (int q = 0; q < 4; ++q) {
        const float h = gate_step(Dr[q], Dz[q], Dn[q], Dm[q],
                                  nBr1, nBz1, bin1, bhn1, h1p[q]);
        h1p[q] = h;
        hsum[q] += h;
        h1w[(lq * 4 + q) * PITCH + j] = (__bf16)h;
      }
      const int s = t - 1;
      if ((s & 255) == 255) {
        const int win = s >> 8;
        #pragma unroll
        for (int q = 0; q < 4; ++q) {
          const int seq  = g * 16 + lq * 4 + q;
          const int b    = seq / NNODE;
          const int node = seq - b * NNODE;
          xg[((size_t)(b * NDYN + win) * NNODE + node) * HH + j] =
              hsum[q] * (1.f / 256.f);
          hsum[q] = 0.f;
        }
      }
    }
    a0 = a0n;
    __syncthreads();
  }

  // ---- epilogue: L1 step 2047 (h0_2047 in sH0[1], h1_2046 in sH1[0])
  {
    const __bf16* h0r = sH0[1];
    const __bf16* h1r = sH1[0];
    bf16x8 ah0[4], ah1[4];
    #pragma unroll
    for (int kc = 0; kc < 4; ++kc) ah0[kc] = *(const bf16x8*)&h0r[aoff + kc * 32];
    #pragma unroll
    for (int kc = 0; kc < 4; ++kc) ah1[kc] = *(const bf16x8*)&h1r[aoff + kc * 32];
    f32x4 Dr = z4, Dz = z4, Dn = z4, Dm = z4;
    #pragma unroll
    for (int kc = 0; kc < 4; ++kc) {
      Dr = mfma16(ah0[kc], bI1[0][kc], Dr);
      Dz = mfma16(ah0[kc], bI1[1][kc], Dz);
      Dn = mfma16(ah0[kc], bI1[2][kc], Dn);
    }
    #pragma unroll
    for (int kc = 0; kc < 4; ++kc) {
      Dr = mfma16(ah1[kc], bH1[0][kc], Dr);
      Dz = mfma16(ah1[kc], bH1[1][kc], Dz);
      Dm = mfma16(ah1[kc], bH1[2][kc], Dm);
    }
    #pragma unroll
    for (int q = 0; q < 4; ++q) {
      const float h = gate_step(Dr[q], Dz[q], Dn[q], Dm[q],
                                nBr1, nBz1, bin1, bhn1, h1p[q]);
      hsum[q] += h;
      const int seq  = g * 16 + lq * 4 + q;
      const int b    = seq / NNODE;
      const int node = seq - b * NNODE;
      xg[((size_t)(b * NDYN + 7) * NNODE + node) * HH + j] =
          hsum[q] * (1.f / 256.f);
    }
  }
}

// ---------------------------------------------------------------------------
// Per-graph stage (unchanged — verified, negligible time).
// ---------------------------------------------------------------------------
static __device__ __forceinline__ float blockReduce256(float v, float* sRed)
{
  const int tid = threadIdx.x;
  __syncthreads();
  sRed[tid] = v;
  __syncthreads();
  #pragma unroll
  for (int st = 128; st >= 1; st >>= 1) {
    if (tid < st) sRed[tid] += sRed[tid + st];
    __syncthreads();
  }
  return sRed[0];
}

__global__ __launch_bounds__(256) void graph_kernel(
    const float* __restrict__ xg,
    const float* __restrict__ Wq, const float* __restrict__ Wk,
    const float* __restrict__ Wl, const float* __restrict__ Wr,
    const float* __restrict__ bs, const float* __restrict__ Wc,
    float* __restrict__ out)
{
  const int tid = threadIdx.x;
  const int bp = blockIdx.x;

  __shared__ float sX[NNODE * HH];
  __shared__ float sQ[NNODE * HH];
  __shared__ float sK[NNODE * HH];
  __shared__ float sG[NNODE * NNODE];
  __shared__ float sA[NNODE * NNODE];
  __shared__ float sS[NNODE * NNODE];
  __shared__ float sNorm[NNODE];
  __shared__ float sDis[NNODE];
  __shared__ float sDeg[NNODE];
  __shared__ float sThr;
  __shared__ float sRed[256];

  for (int idx = tid; idx < NNODE * HH; idx += 256)
    sX[idx] = xg[(size_t)bp * NNODE * HH + idx];
  __syncthreads();

  if (tid < NNODE) {
    float acc = 0.f;
    const float* xv = &sX[tid * HH];
    #pragma unroll 4
    for (int d = 0; d < HH; ++d) acc += xv[d] * xv[d];
    sNorm[tid] = 1.f / sqrtf(acc);
  }
  for (int e = tid; e < NNODE * NNODE; e += 256) {
    const int n = e / NNODE, m = e % NNODE;
    float acc = 0.f;
    const float* a = &sX[n * HH];
    const float* b = &sX[m * HH];
    #pragma unroll 4
    for (int d = 0; d < HH; ++d) acc += a[d] * b[d];
    sG[e] = acc;
  }
  for (int e = tid; e < NNODE * NNODE; e += 256) sA[e] = 0.f;
  __syncthreads();

  if (tid < NNODE) {
    const int r = tid;
    const float nr = sNorm[r];
    float v0 = -1e30f, v1 = -1e30f, v2 = -1e30f;
    int i0 = 0, i1 = 0, i2 = 0;
    for (int m = 0; m < NNODE; ++m) {
      const float v = sG[r * NNODE + m] * nr * sNorm[m];
      if (v > v0)      { v2 = v1; i2 = i1; v1 = v0; i1 = i0; v0 = v; i0 = m; }
      else if (v > v1) { v2 = v1; i2 = i1; v1 = v;  i1 = m; }
      else if (v > v2) { v2 = v;  i2 = m; }
    }
    sA[r * NNODE + i0] = fmaxf(v0, 0.f);
    sA[r * NNODE + i1] = fmaxf(v1, 0.f);
    sA[r * NNODE + i2] = fmaxf(v2, 0.f);
  }
  __syncthreads();

  {
    float t0 = 0.f, t1 = 0.f;
    if (tid < 361) {
      const int n = tid / NNODE, m = tid % NNODE;
      t0 = (n == m) ? 1.f : 0.5f * (sA[n * NNODE + m] + sA[m * NNODE + n]);
    }
    if (tid + 256 < 361) {
      const int e = tid + 256;
      const int n = e / NNODE, m = e % NNODE;
      t1 = (n == m) ? 1.f : 0.5f * (sA[n * NNODE + m] + sA[m * NNODE + n]);
    }
    __syncthreads();
    if (tid < 361) sA[tid] = t0;
    if (tid + 256 < 361) sA[tid + 256] = t1;
  }

  for (int o = tid; o < NNODE * HH; o += 256) {
    const int n = o >> 7, hh = o & 127;
    float aq = 0.f, ak = 0.f;
    const float* xv = &sX[n * HH];
    const float* wq = &Wq[hh * HH];
    const float* wk = &Wk[hh * HH];
    #pragma unroll 4
    for (int d = 0; d < HH; ++d) { const float xx = xv[d]; aq += xx * wq[d]; ak += xx * wk[d]; }
    sQ[o] = aq; sK[o] = ak;
  }
  __syncthreads();

  for (int e = tid; e < NNODE * NNODE; e += 256) {
    const int n = e / NNODE, m = e % NNODE;
    float acc = 0.f;
    const float* a = &sQ[n * HH];
    const float* b = &sK[m * HH];
    #pragma unroll 4
    for (int d = 0; d < HH; ++d) acc += a[d] * b[d];
    sS[e] = acc * 0.08838834764831845f;
  }
  __syncthreads();
  if (tid < NNODE) {
    const int r = tid;
    float mx = -1e30f;
    for (int m = 0; m < NNODE; ++m) mx = fmaxf(mx, sS[r * NNODE + m]);
    float sum = 0.f;
    for (int m = 0; m < NNODE; ++m) sum += expf(sS[r * NNODE + m] - mx);
    const float inv = 1.f / sum;
    for (int m = 0; m < NNODE; ++m)
      sS[r * NNODE + m] = expf(sS[r * NNODE + m] - mx) * inv;
  }
  __syncthreads();

  for (int e = tid; e < NNODE * NNODE; e += 256) {
    const int n = e / NNODE, m = e % NNODE;
    sA[e] = 0.1f * sA[e] + 0.45f * (sS[n * NNODE + m] + sS[m * NNODE + n]);
  }
  __syncthreads();

  for (int e = tid; e < NNODE * NNODE; e += 256) {
    const float v = sA[e];
    int cg = 0, ce = 0;
    for (int f = 0; f < NNODE * NNODE; ++f) {
      const float u = sA[f];
      cg += (u > v);
      ce += (u == v);
    }
    if (cg <= 180 && cg + ce > 180) sThr = v;
  }
  __syncthreads();
  {
    const float thr = sThr;
    for (int e = tid; e < NNODE * NNODE; e += 256)
      sA[e] = (sA[e] > thr) ? sA[e] : 0.f;
  }
  __syncthreads();

  if (tid < NNODE) {
    const int r = tid;
    float dsum = 0.f;
    int cnt = 0;
    for (int m = 0; m < NNODE; ++m) {
      const float v = sA[r * NNODE + m];
      dsum += v;
      if (m != r && v > 0.f) ++cnt;
    }
    sDis[r] = (dsum > 0.f) ? 1.f / sqrtf(dsum) : 0.f;
    sDeg[r] = (float)(cnt < 1 ? 1 : cnt);
  }
  __syncthreads();

  float regp = 0.f;
  for (int e = tid; e < NNODE * NNODE; e += 256) {
    const int n = e / NNODE, m = e % NNODE;
    const float Lnm = ((n == m) ? 1.f : 0.f) - sDis[n] * sDis[m] * sA[e];
    regp += Lnm * sG[e];
  }
  {
    const float tr = blockReduce256(regp, sRed);
    if (tid == 0)
      atomicAdd(out + 16, tr * (1.f / (16384.f * (float)NGRAPH)));
  }
  __syncthreads();

  for (int o = tid; o < NNODE * HH; o += 256) {
    const int n = o >> 7, d = o & 127;
    float acc = 0.f;
    for (int m = 0; m < NNODE; ++m)
      if (m != n && sA[n * NNODE + m] > 0.f) acc += sX[m * HH + d];
    sQ[o] = acc / sDeg[n];
  }
  __syncthreads();

  float lgp = 0.f;
  for (int o = tid; o < NNODE * HH; o += 256) {
    const int n = o >> 7, hh = o & 127;
    float acc = bs[hh];
    const float* av = &sQ[n * HH];
    const float* xv = &sX[n * HH];
    const float* wl = &Wl[hh * HH];
    const float* wr = &Wr[hh * HH];
    #pragma unroll 4
    for (int d = 0; d < HH; ++d) acc += av[d] * wl[d] + xv[d] * wr[d];
    lgp += fmaxf(acc, 0.f) * Wc[hh];
  }
  {
    const float tot = blockReduce256(lgp, sRed);
    if (tid == 0)
      atomicAdd(out + (bp >> 3), tot * 0.125f);
  }
}

__global__ void init_out_kernel(float* __restrict__ out, const float* __restrict__ bc)
{
  const int i = threadIdx.x;
  if (i < 16) out[i] = bc[0];
  else if (i == 16) out[16] = 0.f;
}

// ---------------------------------------------------------------------------
extern "C" void kernel_launch(void* const* d_in, const int* in_sizes, int n_in,
                              void* d_out, int out_size, void* d_ws, size_t ws_size,
                              hipStream_t stream)
{
  const float* x    = (const float*)d_in[0];
  const float* Wih0 = (const float*)d_in[1];
  const float* Whh0 = (const float*)d_in[2];
  const float* bih0 = (const float*)d_in[3];
  const float* bhh0 = (const float*)d_in[4];
  const float* Wih1 = (const float*)d_in[5];
  const float* Whh1 = (const float*)d_in[6];
  const float* bih1 = (const float*)d_in[7];
  const float* bhh1 = (const float*)d_in[8];
  const float* Wq   = (const float*)d_in[9];
  const float* Wk   = (const float*)d_in[10];
  const float* Wl   = (const float*)d_in[11];
  const float* Wr   = (const float*)d_in[12];
  const float* bsg  = (const float*)d_in[13];
  const float* Wc   = (const float*)d_in[14];
  const float* bc   = (const float*)d_in[15];
  float* out = (float*)d_out;

  // workspace layout
  const size_t XB  = (size_t)NNODE * TT * 512 * sizeof(__bf16);  // 39.8 MB
  const size_t WI0 = (size_t)8 * 3 * 64 * 8 * sizeof(__bf16);    // 24 KB
  const size_t WH  = (size_t)8 * 3 * 4 * 64 * 8 * sizeof(__bf16);// 96 KB
  char* p = (char*)d_ws;
  __bf16* xb  = (__bf16*)p;            p += XB;
  __bf16* wI0 = (__bf16*)p;            p += WI0;
  __bf16* wH0 = (__bf16*)p;            p += WH;
  __bf16* wI1 = (__bf16*)p;            p += WH;
  __bf16* wH1 = (__bf16*)p;            p += WH;
  float*  xg  = (float*)p;

  init_out_kernel<<<1, 64, 0, stream>>>(out, bc);
  wprep_kernel<<<6, 256, 0, stream>>>(Wih0, wI0, 32, 1);
  wprep_kernel<<<24, 256, 0, stream>>>(Whh0, wH0, 128, 4);
  wprep_kernel<<<24, 256, 0, stream>>>(Wih1, wI1, 128, 4);
  wprep_kernel<<<24, 256, 0, stream>>>(Whh1, wH1, 128, 4);
  xprep_kernel<<<(NNODE * TT * 64 + 255) / 256, 256, 0, stream>>>(x, xb);
  gru2_kernel<<<NNODE, 512, 0, stream>>>(
      xb, wI0, wH0, wI1, wH1, bih0, bhh0, bih1, bhh1, xg);
  graph_kernel<<<NGRAPH, 256, 0, stream>>>(xg, Wq, Wk, Wl, Wr, bsg, Wc, out);
}